// Round 1
// baseline (46678.928 us; speedup 1.0000x reference)
//
#include <hip/hip_runtime.h>

#define T_STEPS 512
#define BATCH 256
#define IN_DIM 256
#define HID 512
#define OUT_DIM 256

typedef _Float16 half8 __attribute__((ext_vector_type(8)));
typedef float floatx4 __attribute__((ext_vector_type(4)));
typedef float floatx16 __attribute__((ext_vector_type(16)));

__device__ inline float fsig(float x) { return 1.0f / (1.0f + __expf(-x)); }
__device__ inline float ftanh(float x) { return 1.0f - 2.0f / (1.0f + __expf(2.0f * x)); }

__device__ inline half8 cvt8(const float* s) {
  half8 v;
  v[0] = (_Float16)s[0]; v[1] = (_Float16)s[1]; v[2] = (_Float16)s[2]; v[3] = (_Float16)s[3];
  v[4] = (_Float16)s[4]; v[5] = (_Float16)s[5]; v[6] = (_Float16)s[6]; v[7] = (_Float16)s[7];
  return v;
}

// Monotonic 32-block group barrier (device-scope atomics; cross-XCD safe).
__device__ inline void gbar(unsigned int* cnt, unsigned int target) {
  __threadfence();
  __syncthreads();
  if (threadIdx.x == 0) {
    __hip_atomic_fetch_add(cnt, 1u, __ATOMIC_ACQ_REL, __HIP_MEMORY_SCOPE_AGENT);
    while (__hip_atomic_load(cnt, __ATOMIC_ACQUIRE, __HIP_MEMORY_SCOPE_AGENT) < target) {
      __builtin_amdgcn_s_sleep(1);
    }
  }
  __syncthreads();
  __threadfence();
}

__global__ __launch_bounds__(256, 1) void lstm_persistent(
    const float* __restrict__ x, const float* __restrict__ h0,
    const float* __restrict__ c0, const float* __restrict__ z0,
    const float* __restrict__ out_mask, const float* __restrict__ h_mask,
    const float* __restrict__ c_mask, const float* __restrict__ W_ih,
    const float* __restrict__ W_hh, const float* __restrict__ b_ih,
    const float* __restrict__ b_hh, const float* __restrict__ W_fc,
    const float* __restrict__ b_fc, float* __restrict__ out,
    unsigned char* __restrict__ ws)
{
  const int tid = threadIdx.x;
  const int l = tid & 63;
  const int kh = tid >> 6;       // wave id 0..3 = K-quarter
  const int m = l & 31;          // row (A) / gate-col (B) lane index
  const int kg = l >> 5;         // k-subgroup 0/1 (32x32x16)
  const int b = blockIdx.x;
  const int g = b & 7;           // group (batch rows g*32..+31)
  const int ib = b >> 3;         // 0..31 within group (hidden units ib*16..+15)
  const int hbase = ib * 16;
  const int grow0 = g * 32;

  __shared__ float part[4][32][65];   // padded: conflict-free cell reads
  __shared__ float biasg[64];

  unsigned int* cnt = (unsigned int*)ws + g * 32;
  _Float16* zB  = (_Float16*)(ws + 4096);
  _Float16* hB  = (_Float16*)(ws + 4096 + 262144);
  _Float16* hrX = (_Float16*)(ws + 4096 + 262144 + 524288);
  _Float16* zbuf0 = zB + (0 * 8 + g) * (32 * 256);
  _Float16* zbuf1 = zB + (1 * 8 + g) * (32 * 256);
  _Float16* hbuf0 = hB + (0 * 8 + g) * (32 * 512);
  _Float16* hbuf1 = hB + (1 * 8 + g) * (32 * 512);
  _Float16* hrbuf0 = hrX + (0 * 8 + g) * (32 * 512);
  _Float16* hrbuf1 = hrX + (1 * 8 + g) * (32 * 512);

  // ---- init: gate weights -> f16 B-fragments in VGPRs ----
  // gates tile cols 0..63: 0-15=i, 16-31=f (ntile0); 32-47=g, 48-63=o (ntile1)
  half8 bW0[16], bW1[16];
  {
    int col = m;
    int wrow = (col >> 4) * HID + hbase + (col & 15);
    const float* wsrc = (kh < 2) ? (W_ih + wrow * 512 + kh * 256)
                                 : (W_hh + wrow * 512 + (kh - 2) * 256);
#pragma unroll
    for (int ks = 0; ks < 16; ++ks) bW0[ks] = cvt8(wsrc + ks * 16 + kg * 8);
    col = 32 + m;
    wrow = (col >> 4) * HID + hbase + (col & 15);
    wsrc = (kh < 2) ? (W_ih + wrow * 512 + kh * 256)
                    : (W_hh + wrow * 512 + (kh - 2) * 256);
#pragma unroll
    for (int ks = 0; ks < 16; ++ks) bW1[ks] = cvt8(wsrc + ks * 16 + kg * 8);
  }

  // ---- fc weights (blocks ib<16 own 16 out cols each) ----
  const int c16 = l & 15, kg4 = l >> 4;
  half8 bF[4];
  if (ib < 16) {
    int outcol = ib * 16 + c16;
#pragma unroll
    for (int ks = 0; ks < 4; ++ks)
      bF[ks] = cvt8(W_fc + outcol * 512 + kh * 128 + ks * 32 + kg4 * 8);
  }

  // ---- per-thread cell state (row cr, units 2*up,2*up+1) ----
  const int cr = tid >> 3;
  const int up = tid & 7;
  float creg[2], hmr[2], cmr[2];
#pragma unroll
  for (int i = 0; i < 2; ++i) {
    int gi = (grow0 + cr) * HID + hbase + 2 * up + i;
    creg[i] = c0[gi];
    hmr[i] = h_mask[gi];
    cmr[i] = c_mask[gi];
  }
  float omr[2], bfr[2];
  if (ib < 16) {
#pragma unroll
    for (int i = 0; i < 2; ++i) {
      int oc = ib * 16 + 2 * up + i;
      omr[i] = out_mask[(grow0 + cr) * OUT_DIM + oc];
      bfr[i] = b_fc[oc];
    }
  }
  if (tid < 64) {
    int wrow = (tid >> 4) * HID + hbase + (tid & 15);
    biasg[tid] = b_ih[wrow] + b_hh[wrow];
  }
  // stage z0/h0 (f16) for step 0
  if (ib == 0) {
    for (int i = tid; i < 32 * 256; i += 256)
      zbuf0[i] = (_Float16)z0[(grow0 + (i >> 8)) * 256 + (i & 255)];
    for (int i = tid; i < 32 * 512; i += 256)
      hbuf0[i] = (_Float16)h0[(grow0 + (i >> 9)) * 512 + (i & 511)];
  }
  unsigned int tgt = 32;
  gbar(cnt, tgt); tgt += 32;

  const size_t TBO = (size_t)T_STEPS * BATCH * OUT_DIM;

  for (int t = 0; t < T_STEPS; ++t) {
    const int p = t & 1;
    const _Float16* zr = p ? zbuf1 : zbuf0;
    const _Float16* hr = p ? hbuf1 : hbuf0;
    _Float16* hw  = p ? hbuf0 : hbuf1;
    _Float16* hrw = p ? hrbuf0 : hrbuf1;
    _Float16* zw  = p ? zbuf0 : zbuf1;

    // ---- phase 1: gates GEMM (wave kh handles K-quarter; N-tiles 0,1) ----
    floatx16 acc0 = {}, acc1 = {};
    if (kh == 0) {
      const float* s = x + (size_t)t * (BATCH * IN_DIM) + (grow0 + m) * IN_DIM + kg * 8;
#pragma unroll
      for (int ks = 0; ks < 16; ++ks) {
        half8 a = cvt8(s + ks * 16);
        acc0 = __builtin_amdgcn_mfma_f32_32x32x16_f16(a, bW0[ks], acc0, 0, 0, 0);
        acc1 = __builtin_amdgcn_mfma_f32_32x32x16_f16(a, bW1[ks], acc1, 0, 0, 0);
      }
    } else {
      const _Float16* s = (kh == 1) ? (zr + m * 256 + kg * 8)
                                    : (hr + m * 512 + (kh - 2) * 256 + kg * 8);
#pragma unroll
      for (int ks = 0; ks < 16; ++ks) {
        half8 a = *(const half8*)(s + ks * 16);
        acc0 = __builtin_amdgcn_mfma_f32_32x32x16_f16(a, bW0[ks], acc0, 0, 0, 0);
        acc1 = __builtin_amdgcn_mfma_f32_32x32x16_f16(a, bW1[ks], acc1, 0, 0, 0);
      }
    }
    // 32x32x16 C/D layout: col = lane&31, row = (r&3) + 8*(r>>2) + 4*(lane>>5)
#pragma unroll
    for (int r = 0; r < 16; ++r) {
      int row = (r & 3) + 8 * (r >> 2) + 4 * kg;
      part[kh][row][m] = acc0[r];
      part[kh][row][32 + m] = acc1[r];
    }
    __syncthreads();

    // ---- cell update (thread -> row cr, units 2*up, 2*up+1) ----
#pragma unroll
    for (int i = 0; i < 2; ++i) {
      int u = 2 * up + i;
      float gi_ = biasg[u], gf = biasg[16 + u], gg = biasg[32 + u], go = biasg[48 + u];
#pragma unroll
      for (int w = 0; w < 4; ++w) {
        gi_ += part[w][cr][u];
        gf  += part[w][cr][16 + u];
        gg  += part[w][cr][32 + u];
        go  += part[w][cr][48 + u];
      }
      float cn = fsig(gf) * creg[i] + fsig(gi_) * ftanh(gg);
      float hraw = fsig(go) * ftanh(cn);
      int idx = cr * HID + hbase + u;
      hrw[idx] = (_Float16)hraw;
      float hmv = hraw * hmr[i];
      hw[idx] = (_Float16)hmv;
      creg[i] = cn * cmr[i];
      if (t == T_STEPS - 1) {
        out[TBO + (size_t)(grow0 + cr) * HID + hbase + u] = hmv;
        out[TBO + (size_t)BATCH * HID + (size_t)(grow0 + cr) * HID + hbase + u] = creg[i];
      }
    }
    gbar(cnt, tgt); tgt += 32;

    // ---- phase 2: fc GEMM + tanh + out_mask (blocks ib<16) ----
    if (ib < 16) {
      floatx4 fa0 = {}, fa1 = {};
      const _Float16* s = hrw + c16 * 512 + kh * 128 + kg4 * 8;
#pragma unroll
      for (int ks = 0; ks < 4; ++ks) {
        half8 a0 = *(const half8*)(s + ks * 32);
        half8 a1 = *(const half8*)(s + 16 * 512 + ks * 32);
        fa0 = __builtin_amdgcn_mfma_f32_16x16x32_f16(a0, bF[ks], fa0, 0, 0, 0);
        fa1 = __builtin_amdgcn_mfma_f32_16x16x32_f16(a1, bF[ks], fa1, 0, 0, 0);
      }
      float* p2 = (float*)part;  // [4][32][16]
#pragma unroll
      for (int r = 0; r < 4; ++r) {
        p2[(kh * 32 + kg4 * 4 + r) * 16 + c16] = fa0[r];
        p2[(kh * 32 + 16 + kg4 * 4 + r) * 16 + c16] = fa1[r];
      }
      __syncthreads();
#pragma unroll
      for (int i = 0; i < 2; ++i) {
        int c = 2 * up + i;
        float sacc = bfr[i];
#pragma unroll
        for (int w = 0; w < 4; ++w) sacc += p2[(w * 32 + cr) * 16 + c];
        float zv = ftanh(sacc) * omr[i];
        out[(size_t)t * (BATCH * OUT_DIM) + (size_t)(grow0 + cr) * OUT_DIM + ib * 16 + c] = zv;
        zw[cr * 256 + ib * 16 + c] = (_Float16)zv;
      }
    }
    gbar(cnt, tgt); tgt += 32;
  }
}

extern "C" void kernel_launch(void* const* d_in, const int* in_sizes, int n_in,
                              void* d_out, int out_size, void* d_ws, size_t ws_size,
                              hipStream_t stream) {
  if (ws_size < (size_t)(4096 + 262144 + 524288 + 524288)) return;
  const float* x     = (const float*)d_in[0];
  const float* h0    = (const float*)d_in[1];
  const float* c0    = (const float*)d_in[2];
  const float* z0    = (const float*)d_in[3];
  const float* omsk  = (const float*)d_in[4];
  const float* hmsk  = (const float*)d_in[5];
  const float* cmsk  = (const float*)d_in[6];
  const float* Wih   = (const float*)d_in[7];
  const float* Whh   = (const float*)d_in[8];
  const float* bih   = (const float*)d_in[9];
  const float* bhh   = (const float*)d_in[10];
  const float* Wfc   = (const float*)d_in[11];
  const float* bfc   = (const float*)d_in[12];
  float* out = (float*)d_out;
  unsigned char* ws = (unsigned char*)d_ws;

  hipMemsetAsync(d_ws, 0, 4096, stream);

  void* args[] = { &x, &h0, &c0, &z0, &omsk, &hmsk, &cmsk,
                   &Wih, &Whh, &bih, &bhh, &Wfc, &bfc, &out, &ws };
  hipError_t err = hipLaunchCooperativeKernel(
      reinterpret_cast<const void*>(&lstm_persistent),
      dim3(256), dim3(256), args, 0, stream);
  if (err != hipSuccess) {
    // Fallback: plain launch (256 blocks <= 256 CUs, >=1 block/CU fits -> co-resident)
    lstm_persistent<<<dim3(256), dim3(256), 0, stream>>>(
        x, h0, c0, z0, omsk, hmsk, cmsk, Wih, Whh, bih, bhh, Wfc, bfc, out, ws);
  }
}

// Round 2
// 6814.339 us; speedup vs baseline: 6.8501x; 6.8501x over previous
//
#include <hip/hip_runtime.h>

#define T_STEPS 512
#define BATCH 256
#define IN_DIM 256
#define HID 512
#define OUT_DIM 256

typedef _Float16 half8 __attribute__((ext_vector_type(8)));
typedef float floatx4 __attribute__((ext_vector_type(4)));
typedef float floatx16 __attribute__((ext_vector_type(16)));

__device__ inline float fsig(float x) { return 1.0f / (1.0f + __expf(-x)); }
__device__ inline float ftanh(float x) { return 1.0f - 2.0f / (1.0f + __expf(2.0f * x)); }

__device__ inline half8 cvt8(const float* s) {
  half8 v;
  v[0] = (_Float16)s[0]; v[1] = (_Float16)s[1]; v[2] = (_Float16)s[2]; v[3] = (_Float16)s[3];
  v[4] = (_Float16)s[4]; v[5] = (_Float16)s[5]; v[6] = (_Float16)s[6]; v[7] = (_Float16)s[7];
  return v;
}

// --- device-coherent (sc1, L2-bypass) access helpers for cross-block data ---
__device__ inline void st_pair(_Float16* p, float a, float b) {
  union { unsigned u; _Float16 h[2]; } v;
  v.h[0] = (_Float16)a; v.h[1] = (_Float16)b;
  __hip_atomic_store((unsigned*)p, v.u, __ATOMIC_RELAXED, __HIP_MEMORY_SCOPE_AGENT);
}
__device__ inline half8 ld16c(const _Float16* p) {
  union { unsigned long long u[2]; half8 h; } v;
  const unsigned long long* q = (const unsigned long long*)p;
  v.u[0] = __hip_atomic_load(q, __ATOMIC_RELAXED, __HIP_MEMORY_SCOPE_AGENT);
  v.u[1] = __hip_atomic_load(q + 1, __ATOMIC_RELAXED, __HIP_MEMORY_SCOPE_AGENT);
  return v.h;
}

// Monotonic 32-block group barrier: NO fences. Prior sc1 stores are ordered by
// an explicit vmcnt(0); counter ops are relaxed agent-scope (sc1, MALL-coherent).
__device__ inline void gbar(unsigned int* cnt, unsigned int target) {
  __syncthreads();
  asm volatile("s_waitcnt vmcnt(0)" ::: "memory");
  if (threadIdx.x == 0) {
    __hip_atomic_fetch_add(cnt, 1u, __ATOMIC_RELAXED, __HIP_MEMORY_SCOPE_AGENT);
    while (__hip_atomic_load(cnt, __ATOMIC_RELAXED, __HIP_MEMORY_SCOPE_AGENT) < target) {
      __builtin_amdgcn_s_sleep(1);
    }
  }
  __syncthreads();
}

__global__ __launch_bounds__(256, 1) void lstm_persistent(
    const float* __restrict__ x, const float* __restrict__ h0,
    const float* __restrict__ c0, const float* __restrict__ z0,
    const float* __restrict__ out_mask, const float* __restrict__ h_mask,
    const float* __restrict__ c_mask, const float* __restrict__ W_ih,
    const float* __restrict__ W_hh, const float* __restrict__ b_ih,
    const float* __restrict__ b_hh, const float* __restrict__ W_fc,
    const float* __restrict__ b_fc, float* __restrict__ out,
    unsigned char* __restrict__ ws)
{
  const int tid = threadIdx.x;
  const int l = tid & 63;
  const int kh = tid >> 6;       // wave id 0..3 = K-quarter
  const int m = l & 31;          // row (A) / gate-col (B) lane index
  const int kg = l >> 5;         // k-subgroup 0/1 (32x32x16)
  const int b = blockIdx.x;
  const int g = b & 7;           // group (batch rows g*32..+31)
  const int ib = b >> 3;         // 0..31 within group (hidden units ib*16..+15)
  const int hbase = ib * 16;
  const int grow0 = g * 32;

  __shared__ float part[4][32][65];   // padded: conflict-free cell reads
  __shared__ float biasg[64];

  unsigned int* cnt = (unsigned int*)ws + g * 32;
  _Float16* zB  = (_Float16*)(ws + 4096);
  _Float16* hB  = (_Float16*)(ws + 4096 + 262144);
  _Float16* hrX = (_Float16*)(ws + 4096 + 262144 + 524288);
  _Float16* zbuf0 = zB + (0 * 8 + g) * (32 * 256);
  _Float16* zbuf1 = zB + (1 * 8 + g) * (32 * 256);
  _Float16* hbuf0 = hB + (0 * 8 + g) * (32 * 512);
  _Float16* hbuf1 = hB + (1 * 8 + g) * (32 * 512);
  _Float16* hrbuf0 = hrX + (0 * 8 + g) * (32 * 512);
  _Float16* hrbuf1 = hrX + (1 * 8 + g) * (32 * 512);

  // ---- init: gate weights -> f16 B-fragments in VGPRs ----
  // gates tile cols 0..63: 0-15=i, 16-31=f (ntile0); 32-47=g, 48-63=o (ntile1)
  half8 bW0[16], bW1[16];
  {
    int col = m;
    int wrow = (col >> 4) * HID + hbase + (col & 15);
    const float* wsrc = (kh < 2) ? (W_ih + wrow * 512 + kh * 256)
                                 : (W_hh + wrow * 512 + (kh - 2) * 256);
#pragma unroll
    for (int ks = 0; ks < 16; ++ks) bW0[ks] = cvt8(wsrc + ks * 16 + kg * 8);
    col = 32 + m;
    wrow = (col >> 4) * HID + hbase + (col & 15);
    wsrc = (kh < 2) ? (W_ih + wrow * 512 + kh * 256)
                    : (W_hh + wrow * 512 + (kh - 2) * 256);
#pragma unroll
    for (int ks = 0; ks < 16; ++ks) bW1[ks] = cvt8(wsrc + ks * 16 + kg * 8);
  }

  // ---- fc weights (blocks ib<16 own 16 out cols each) ----
  const int c16 = l & 15, kg4 = l >> 4;
  half8 bF[4];
  if (ib < 16) {
    int outcol = ib * 16 + c16;
#pragma unroll
    for (int ks = 0; ks < 4; ++ks)
      bF[ks] = cvt8(W_fc + outcol * 512 + kh * 128 + ks * 32 + kg4 * 8);
  }

  // ---- per-thread cell state (row cr, units 2*up,2*up+1) ----
  const int cr = tid >> 3;
  const int up = tid & 7;
  float creg[2], hmr[2], cmr[2];
#pragma unroll
  for (int i = 0; i < 2; ++i) {
    int gi = (grow0 + cr) * HID + hbase + 2 * up + i;
    creg[i] = c0[gi];
    hmr[i] = h_mask[gi];
    cmr[i] = c_mask[gi];
  }
  float omr[2], bfr[2];
  if (ib < 16) {
#pragma unroll
    for (int i = 0; i < 2; ++i) {
      int oc = ib * 16 + 2 * up + i;
      omr[i] = out_mask[(grow0 + cr) * OUT_DIM + oc];
      bfr[i] = b_fc[oc];
    }
  }
  if (tid < 64) {
    int wrow = (tid >> 4) * HID + hbase + (tid & 15);
    biasg[tid] = b_ih[wrow] + b_hh[wrow];
  }
  // stage z0/h0 (f16, sc1) for step 0
  if (ib == 0) {
    for (int i = tid; i < 32 * 128; i += 256) {
      int r = i >> 7, cp = (i & 127) * 2;
      const float* s = z0 + (grow0 + r) * 256 + cp;
      st_pair(zbuf0 + r * 256 + cp, s[0], s[1]);
    }
    for (int i = tid; i < 32 * 256; i += 256) {
      int r = i >> 8, cp = (i & 255) * 2;
      const float* s = h0 + (grow0 + r) * 512 + cp;
      st_pair(hbuf0 + r * 512 + cp, s[0], s[1]);
    }
  }
  unsigned int tgt = 32;
  gbar(cnt, tgt); tgt += 32;

  const size_t TBO = (size_t)T_STEPS * BATCH * OUT_DIM;

  for (int t = 0; t < T_STEPS; ++t) {
    const int p = t & 1;
    const _Float16* zr = p ? zbuf1 : zbuf0;
    const _Float16* hr = p ? hbuf1 : hbuf0;
    _Float16* hw  = p ? hbuf0 : hbuf1;
    _Float16* hrw = p ? hrbuf0 : hrbuf1;
    _Float16* zw  = p ? zbuf0 : zbuf1;

    // ---- phase 1: gates GEMM (wave kh handles K-quarter; N-tiles 0,1) ----
    floatx16 acc0 = {}, acc1 = {};
    if (kh == 0) {
      const float* s = x + (size_t)t * (BATCH * IN_DIM) + (grow0 + m) * IN_DIM + kg * 8;
#pragma unroll
      for (int ks = 0; ks < 16; ++ks) {
        half8 a = cvt8(s + ks * 16);
        acc0 = __builtin_amdgcn_mfma_f32_32x32x16_f16(a, bW0[ks], acc0, 0, 0, 0);
        acc1 = __builtin_amdgcn_mfma_f32_32x32x16_f16(a, bW1[ks], acc1, 0, 0, 0);
      }
    } else {
      const _Float16* s = (kh == 1) ? (zr + m * 256 + kg * 8)
                                    : (hr + m * 512 + (kh - 2) * 256 + kg * 8);
#pragma unroll
      for (int ks = 0; ks < 16; ++ks) {
        half8 a = ld16c(s + ks * 16);
        acc0 = __builtin_amdgcn_mfma_f32_32x32x16_f16(a, bW0[ks], acc0, 0, 0, 0);
        acc1 = __builtin_amdgcn_mfma_f32_32x32x16_f16(a, bW1[ks], acc1, 0, 0, 0);
      }
    }
    // 32x32x16 C/D layout: col = lane&31, row = (r&3) + 8*(r>>2) + 4*(lane>>5)
#pragma unroll
    for (int r = 0; r < 16; ++r) {
      int row = (r & 3) + 8 * (r >> 2) + 4 * kg;
      part[kh][row][m] = acc0[r];
      part[kh][row][32 + m] = acc1[r];
    }
    __syncthreads();

    // ---- cell update (thread -> row cr, units 2*up, 2*up+1) ----
    {
      float hraw2[2], hmv2[2];
#pragma unroll
      for (int i = 0; i < 2; ++i) {
        int u = 2 * up + i;
        float gi_ = biasg[u], gf = biasg[16 + u], gg = biasg[32 + u], go = biasg[48 + u];
#pragma unroll
        for (int w = 0; w < 4; ++w) {
          gi_ += part[w][cr][u];
          gf  += part[w][cr][16 + u];
          gg  += part[w][cr][32 + u];
          go  += part[w][cr][48 + u];
        }
        float cn = fsig(gf) * creg[i] + fsig(gi_) * ftanh(gg);
        float hraw = fsig(go) * ftanh(cn);
        hraw2[i] = hraw;
        hmv2[i] = hraw * hmr[i];
        creg[i] = cn * cmr[i];
        if (t == T_STEPS - 1) {
          int u2 = 2 * up + i;
          out[TBO + (size_t)(grow0 + cr) * HID + hbase + u2] = hmv2[i];
          out[TBO + (size_t)BATCH * HID + (size_t)(grow0 + cr) * HID + hbase + u2] = creg[i];
        }
      }
      int idx0 = cr * HID + hbase + 2 * up;
      st_pair(hrw + idx0, hraw2[0], hraw2[1]);
      st_pair(hw + idx0, hmv2[0], hmv2[1]);
    }
    gbar(cnt, tgt); tgt += 32;

    // ---- phase 2: fc GEMM + tanh + out_mask (blocks ib<16) ----
    if (ib < 16) {
      floatx4 fa0 = {}, fa1 = {};
      const _Float16* s = hrw + c16 * 512 + kh * 128 + kg4 * 8;
#pragma unroll
      for (int ks = 0; ks < 4; ++ks) {
        half8 a0 = ld16c(s + ks * 32);
        half8 a1 = ld16c(s + 16 * 512 + ks * 32);
        fa0 = __builtin_amdgcn_mfma_f32_16x16x32_f16(a0, bF[ks], fa0, 0, 0, 0);
        fa1 = __builtin_amdgcn_mfma_f32_16x16x32_f16(a1, bF[ks], fa1, 0, 0, 0);
      }
      float* p2 = (float*)part;  // [4][32][16]
#pragma unroll
      for (int r = 0; r < 4; ++r) {
        p2[(kh * 32 + kg4 * 4 + r) * 16 + c16] = fa0[r];
        p2[(kh * 32 + 16 + kg4 * 4 + r) * 16 + c16] = fa1[r];
      }
      __syncthreads();
      {
        float zv2[2];
#pragma unroll
        for (int i = 0; i < 2; ++i) {
          int c = 2 * up + i;
          float sacc = bfr[i];
#pragma unroll
          for (int w = 0; w < 4; ++w) sacc += p2[(w * 32 + cr) * 16 + c];
          zv2[i] = ftanh(sacc) * omr[i];
          out[(size_t)t * (BATCH * OUT_DIM) + (size_t)(grow0 + cr) * OUT_DIM + ib * 16 + c] = zv2[i];
        }
        st_pair(zw + cr * 256 + ib * 16 + 2 * up, zv2[0], zv2[1]);
      }
    }
    gbar(cnt, tgt); tgt += 32;
  }
}

extern "C" void kernel_launch(void* const* d_in, const int* in_sizes, int n_in,
                              void* d_out, int out_size, void* d_ws, size_t ws_size,
                              hipStream_t stream) {
  if (ws_size < (size_t)(4096 + 262144 + 524288 + 524288)) return;
  const float* x     = (const float*)d_in[0];
  const float* h0    = (const float*)d_in[1];
  const float* c0    = (const float*)d_in[2];
  const float* z0    = (const float*)d_in[3];
  const float* omsk  = (const float*)d_in[4];
  const float* hmsk  = (const float*)d_in[5];
  const float* cmsk  = (const float*)d_in[6];
  const float* Wih   = (const float*)d_in[7];
  const float* Whh   = (const float*)d_in[8];
  const float* bih   = (const float*)d_in[9];
  const float* bhh   = (const float*)d_in[10];
  const float* Wfc   = (const float*)d_in[11];
  const float* bfc   = (const float*)d_in[12];
  float* out = (float*)d_out;
  unsigned char* ws = (unsigned char*)d_ws;

  hipMemsetAsync(d_ws, 0, 4096, stream);

  void* args[] = { &x, &h0, &c0, &z0, &omsk, &hmsk, &cmsk,
                   &Wih, &Whh, &bih, &bhh, &Wfc, &bfc, &out, &ws };
  hipError_t err = hipLaunchCooperativeKernel(
      reinterpret_cast<const void*>(&lstm_persistent),
      dim3(256), dim3(256), args, 0, stream);
  if (err != hipSuccess) {
    // Fallback: plain launch (256 blocks <= 256 CUs -> co-resident)
    lstm_persistent<<<dim3(256), dim3(256), 0, stream>>>(
        x, h0, c0, z0, omsk, hmsk, cmsk, Wih, Whh, bih, bhh, Wfc, bfc, out, ws);
  }
}

// Round 3
// 4458.313 us; speedup vs baseline: 10.4701x; 1.5285x over previous
//
#include <hip/hip_runtime.h>

#define T_STEPS 512
#define BATCH 256
#define IN_DIM 256
#define HID 512
#define OUT_DIM 256

typedef _Float16 half8 __attribute__((ext_vector_type(8)));
typedef float floatx4 __attribute__((ext_vector_type(4)));
typedef float floatx16 __attribute__((ext_vector_type(16)));

__device__ inline float fsig(float x) { return 1.0f / (1.0f + __expf(-x)); }
__device__ inline float ftanh(float x) { return 1.0f - 2.0f / (1.0f + __expf(2.0f * x)); }

__device__ inline half8 cvt8(const float* s) {
  half8 v;
  v[0] = (_Float16)s[0]; v[1] = (_Float16)s[1]; v[2] = (_Float16)s[2]; v[3] = (_Float16)s[3];
  v[4] = (_Float16)s[4]; v[5] = (_Float16)s[5]; v[6] = (_Float16)s[6]; v[7] = (_Float16)s[7];
  return v;
}

// Coherent 16B load (bypass L1/L2 -> MALL). NO waitcnt: batch-issue then vmwait0().
__device__ inline half8 ld16a(const _Float16* p) {
  half8 r;
  asm volatile("global_load_dwordx4 %0, %1, off sc0 sc1" : "=v"(r) : "v"(p));
  return r;
}
__device__ inline void vmwait0() {
  asm volatile("s_waitcnt vmcnt(0)" ::: "memory");
  __builtin_amdgcn_sched_barrier(0);   // rule #18: stop MFMA hoisting above the wait
}

// Coherent small stores (compiler-emitted sc1 path)
__device__ inline void st_pair(_Float16* p, float a, float b) {
  union { unsigned u; _Float16 h[2]; } v;
  v.h[0] = (_Float16)a; v.h[1] = (_Float16)b;
  __hip_atomic_store((unsigned*)p, v.u, __ATOMIC_RELAXED, __HIP_MEMORY_SCOPE_AGENT);
}
__device__ inline void st_one(_Float16* p, float f) {
  union { unsigned short u; _Float16 h; } v; v.h = (_Float16)f;
  __hip_atomic_store((unsigned short*)p, v.u, __ATOMIC_RELAXED, __HIP_MEMORY_SCOPE_AGENT);
}
__device__ inline void setflag(unsigned* p, unsigned v) {
  __hip_atomic_store(p, v, __ATOMIC_RELAXED, __HIP_MEMORY_SCOPE_AGENT);
}
// Wave-wide poll: lanes 0..31 each watch one flag; exit when all >= tgt.
__device__ inline void poll32(const unsigned* flags, unsigned tgt) {
  const int l = threadIdx.x & 63;
  unsigned v;
  do {
    v = (l < 32) ? __hip_atomic_load(flags + l, __ATOMIC_RELAXED, __HIP_MEMORY_SCOPE_AGENT)
                 : tgt;
  } while (!__all((int)(v >= tgt)));
  asm volatile("" ::: "memory");
}

__global__ __launch_bounds__(256, 1) void lstm_persistent(
    const float* __restrict__ x, const float* __restrict__ h0,
    const float* __restrict__ c0, const float* __restrict__ z0,
    const float* __restrict__ out_mask, const float* __restrict__ h_mask,
    const float* __restrict__ c_mask, const float* __restrict__ W_ih,
    const float* __restrict__ W_hh, const float* __restrict__ b_ih,
    const float* __restrict__ b_hh, const float* __restrict__ W_fc,
    const float* __restrict__ b_fc, float* __restrict__ out,
    unsigned char* __restrict__ ws)
{
  const int tid = threadIdx.x;
  const int l = tid & 63;
  const int kh = tid >> 6;       // wave id: 0=x(+fc), 1=z, 2=h[0:256], 3=h[256:512]
  const int m = l & 31;          // A-row / B-col lane index (32x32 tiles)
  const int kg = l >> 5;         // k-subgroup 0/1
  const int b = blockIdx.x;
  const int g = b & 7;           // group: batch rows g*32..+31 (same XCD by bid%8)
  const int ib = b >> 3;         // 0..31 within group (hidden units ib*16..+15)
  const int hbase = ib * 16;
  const int grow0 = g * 32;

  __shared__ float part[4][32][65];
  __shared__ float biasg[64];

  unsigned* flag1g = (unsigned*)ws + g * 32;            // h/hraw ready: cell(t) -> t+2 (stage=1)
  unsigned* flag2g = (unsigned*)(ws + 1024) + g * 32;   // z ready:       fc(t) -> t+2 (stage=1)
  _Float16* zB  = (_Float16*)(ws + 4096);
  _Float16* hB  = (_Float16*)(ws + 4096 + 262144);
  _Float16* hrX = (_Float16*)(ws + 4096 + 262144 + 524288);
  _Float16* zbuf0 = zB + (0 * 8 + g) * (32 * 256);
  _Float16* zbuf1 = zB + (1 * 8 + g) * (32 * 256);
  _Float16* hbuf0 = hB + (0 * 8 + g) * (32 * 512);
  _Float16* hbuf1 = hB + (1 * 8 + g) * (32 * 512);
  _Float16* hrbuf0 = hrX + (0 * 8 + g) * (32 * 512);
  _Float16* hrbuf1 = hrX + (1 * 8 + g) * (32 * 512);

  // ---- gate weights -> f16 B-fragments in VGPRs ----
  half8 bW0[16], bW1[16];
  {
    int col = m;
    int wrow = (col >> 4) * HID + hbase + (col & 15);
    const float* wsrc = (kh < 2) ? (W_ih + wrow * 512 + kh * 256)
                                 : (W_hh + wrow * 512 + (kh - 2) * 256);
#pragma unroll
    for (int ks = 0; ks < 16; ++ks) bW0[ks] = cvt8(wsrc + ks * 16 + kg * 8);
    col = 32 + m;
    wrow = (col >> 4) * HID + hbase + (col & 15);
    wsrc = (kh < 2) ? (W_ih + wrow * 512 + kh * 256)
                    : (W_hh + wrow * 512 + (kh - 2) * 256);
#pragma unroll
    for (int ks = 0; ks < 16; ++ks) bW1[ks] = cvt8(wsrc + ks * 16 + kg * 8);
  }

  // ---- fc: block computes out tile rows fcrow0..+15 x cols fccol0..+15 (wave 0) ----
  const int fcrow0 = (ib >> 4) * 16;     // local row in group
  const int fccol0 = (ib & 15) * 16;
  half8 bF[16];
  float omr4[4], bfr = 0.f;
  if (kh == 0) {
    int colL = fccol0 + (l & 15);
#pragma unroll
    for (int ks = 0; ks < 16; ++ks)
      bF[ks] = cvt8(W_fc + colL * 512 + ks * 32 + (l >> 4) * 8);
    bfr = b_fc[colL];
#pragma unroll
    for (int r = 0; r < 4; ++r) {
      int rowL = fcrow0 + (l >> 4) * 4 + r;
      omr4[r] = out_mask[(size_t)(grow0 + rowL) * OUT_DIM + colL];
    }
  }

  // ---- per-thread cell state (row cr, units 2*up, 2*up+1) ----
  const int cr = tid >> 3;
  const int up = tid & 7;
  float creg[2], hmr[2], cmr[2];
#pragma unroll
  for (int i = 0; i < 2; ++i) {
    int gi = (grow0 + cr) * HID + hbase + 2 * up + i;
    creg[i] = c0[gi];
    hmr[i] = h_mask[gi];
    cmr[i] = c_mask[gi];
  }
  if (tid < 64) {
    int wrow = (tid >> 4) * HID + hbase + (tid & 15);
    biasg[tid] = b_ih[wrow] + b_hh[wrow];
  }

  // ---- stage z(-1)=z0, h(-1)=h0 into parity-1 buffers; block ib stages row ib ----
  {
    const float* hsrc = h0 + (size_t)(grow0 + ib) * HID;
    st_pair(hbuf1 + ib * HID + 2 * tid, hsrc[2 * tid], hsrc[2 * tid + 1]);
    if (tid < 128) {
      const float* zsrc = z0 + (size_t)(grow0 + ib) * OUT_DIM;
      st_pair(zbuf1 + ib * OUT_DIM + 2 * tid, zsrc[2 * tid], zsrc[2 * tid + 1]);
    }
  }
  asm volatile("s_waitcnt vmcnt(0)" ::: "memory");
  __syncthreads();
  if (tid == 0) { setflag(&flag1g[ib], 1u); setflag(&flag2g[ib], 1u); }

  const size_t TBO = (size_t)T_STEPS * BATCH * OUT_DIM;

  for (int t = 0; t < T_STEPS; ++t) {
    const int p = t & 1;
    const _Float16* zr = p ? zbuf0 : zbuf1;   // z(t-1) in buf[(t+1)&1]
    const _Float16* hr = p ? hbuf0 : hbuf1;
    _Float16* hw  = p ? hbuf1 : hbuf0;        // h(t) -> buf[t&1]
    _Float16* hrw = p ? hrbuf1 : hrbuf0;
    _Float16* zw  = p ? zbuf1 : zbuf0;

    // ---- phase A: gates GEMM; per-wave dependency-shaped waits ----
    floatx16 acc0 = {}, acc1 = {};
    if (kh == 0) {
      const float* s = x + (size_t)t * (BATCH * IN_DIM) + (grow0 + m) * IN_DIM + kg * 8;
      half8 a[16];
#pragma unroll
      for (int ks = 0; ks < 16; ++ks) a[ks] = cvt8(s + ks * 16);
#pragma unroll
      for (int ks = 0; ks < 16; ++ks) {
        acc0 = __builtin_amdgcn_mfma_f32_32x32x16_f16(a[ks], bW0[ks], acc0, 0, 0, 0);
        acc1 = __builtin_amdgcn_mfma_f32_32x32x16_f16(a[ks], bW1[ks], acc1, 0, 0, 0);
      }
    } else if (kh == 1) {
      poll32(flag2g, (unsigned)(t + 1));      // z(t-1) ready
      const _Float16* s = zr + m * 256 + kg * 8;
      half8 a[16];
#pragma unroll
      for (int ks = 0; ks < 16; ++ks) a[ks] = ld16a(s + ks * 16);
      vmwait0();
#pragma unroll
      for (int ks = 0; ks < 16; ++ks) {
        acc0 = __builtin_amdgcn_mfma_f32_32x32x16_f16(a[ks], bW0[ks], acc0, 0, 0, 0);
        acc1 = __builtin_amdgcn_mfma_f32_32x32x16_f16(a[ks], bW1[ks], acc1, 0, 0, 0);
      }
    } else {
      poll32(flag1g, (unsigned)(t + 1));      // h(t-1) ready
      const _Float16* s = hr + m * 512 + (kh - 2) * 256 + kg * 8;
      half8 a[16];
#pragma unroll
      for (int ks = 0; ks < 16; ++ks) a[ks] = ld16a(s + ks * 16);
      vmwait0();
#pragma unroll
      for (int ks = 0; ks < 16; ++ks) {
        acc0 = __builtin_amdgcn_mfma_f32_32x32x16_f16(a[ks], bW0[ks], acc0, 0, 0, 0);
        acc1 = __builtin_amdgcn_mfma_f32_32x32x16_f16(a[ks], bW1[ks], acc1, 0, 0, 0);
      }
    }
    // 32x32x16 C/D: col = lane&31, row = (r&3) + 8*(r>>2) + 4*(lane>>5)
#pragma unroll
    for (int r = 0; r < 16; ++r) {
      int row = (r & 3) + 8 * (r >> 2) + 4 * kg;
      part[kh][row][m] = acc0[r];
      part[kh][row][32 + m] = acc1[r];
    }
    __syncthreads();

    // ---- cell update ----
    {
      float hraw2[2], hmv2[2];
#pragma unroll
      for (int i = 0; i < 2; ++i) {
        int u = 2 * up + i;
        float gi_ = biasg[u], gf = biasg[16 + u], gg = biasg[32 + u], go = biasg[48 + u];
#pragma unroll
        for (int w = 0; w < 4; ++w) {
          gi_ += part[w][cr][u];
          gf  += part[w][cr][16 + u];
          gg  += part[w][cr][32 + u];
          go  += part[w][cr][48 + u];
        }
        float cn = fsig(gf) * creg[i] + fsig(gi_) * ftanh(gg);
        float hraw = fsig(go) * ftanh(cn);
        hraw2[i] = hraw;
        hmv2[i] = hraw * hmr[i];
        creg[i] = cn * cmr[i];
        if (t == T_STEPS - 1) {
          out[TBO + (size_t)(grow0 + cr) * HID + hbase + u] = hmv2[i];
          out[TBO + (size_t)BATCH * HID + (size_t)(grow0 + cr) * HID + hbase + u] = creg[i];
        }
      }
      int idx0 = cr * HID + hbase + 2 * up;
      st_pair(hrw + idx0, hraw2[0], hraw2[1]);
      st_pair(hw + idx0, hmv2[0], hmv2[1]);
    }
    asm volatile("s_waitcnt vmcnt(0)" ::: "memory");
    __syncthreads();
    if (tid == 0) setflag(&flag1g[ib], (unsigned)(t + 2));

    // ---- phase B: fc on wave 0 only (16x16 out tile, K=512) ----
    if (kh == 0) {
      poll32(flag1g, (unsigned)(t + 2));      // hraw(t) from all blocks
      const _Float16* s = hrw + (fcrow0 + (l & 15)) * 512 + (l >> 4) * 8;
      half8 a[16];
#pragma unroll
      for (int ks = 0; ks < 16; ++ks) a[ks] = ld16a(s + ks * 32);
      vmwait0();
      floatx4 fa = {};
#pragma unroll
      for (int ks = 0; ks < 16; ++ks)
        fa = __builtin_amdgcn_mfma_f32_16x16x32_f16(a[ks], bF[ks], fa, 0, 0, 0);
      int colL = fccol0 + (l & 15);
#pragma unroll
      for (int r = 0; r < 4; ++r) {
        int rowL = fcrow0 + (l >> 4) * 4 + r;
        float zv = ftanh(fa[r] + bfr) * omr4[r];
        out[(size_t)t * (BATCH * OUT_DIM) + (size_t)(grow0 + rowL) * OUT_DIM + colL] = zv;
        st_one(zw + rowL * 256 + colL, zv);
      }
      asm volatile("s_waitcnt vmcnt(0)" ::: "memory");
      if (l == 0) setflag(&flag2g[ib], (unsigned)(t + 2));
    }
  }
}

extern "C" void kernel_launch(void* const* d_in, const int* in_sizes, int n_in,
                              void* d_out, int out_size, void* d_ws, size_t ws_size,
                              hipStream_t stream) {
  if (ws_size < (size_t)(4096 + 262144 + 524288 + 524288)) return;
  const float* x     = (const float*)d_in[0];
  const float* h0    = (const float*)d_in[1];
  const float* c0    = (const float*)d_in[2];
  const float* z0    = (const float*)d_in[3];
  const float* omsk  = (const float*)d_in[4];
  const float* hmsk  = (const float*)d_in[5];
  const float* cmsk  = (const float*)d_in[6];
  const float* Wih   = (const float*)d_in[7];
  const float* Whh   = (const float*)d_in[8];
  const float* bih   = (const float*)d_in[9];
  const float* bhh   = (const float*)d_in[10];
  const float* Wfc   = (const float*)d_in[11];
  const float* bfc   = (const float*)d_in[12];
  float* out = (float*)d_out;
  unsigned char* ws = (unsigned char*)d_ws;

  hipMemsetAsync(d_ws, 0, 4096, stream);

  void* args[] = { &x, &h0, &c0, &z0, &omsk, &hmsk, &cmsk,
                   &Wih, &Whh, &bih, &bhh, &Wfc, &bfc, &out, &ws };
  hipError_t err = hipLaunchCooperativeKernel(
      reinterpret_cast<const void*>(&lstm_persistent),
      dim3(256), dim3(256), args, 0, stream);
  if (err != hipSuccess) {
    lstm_persistent<<<dim3(256), dim3(256), 0, stream>>>(
        x, h0, c0, z0, omsk, hmsk, cmsk, Wih, Whh, bih, bhh, Wfc, bfc, out, ws);
  }
}